// Round 8
// baseline (1350.948 us; speedup 1.0000x reference)
//
#include <hip/hip_runtime.h>

#define LNUM 8

typedef __attribute__((ext_vector_type(4))) float f32x4;
typedef __attribute__((ext_vector_type(2))) float f32x2;
typedef __attribute__((ext_vector_type(8))) _Float16 f16x8;
typedef __attribute__((ext_vector_type(2))) _Float16 f16x2;

#define MFMAH(A,B,C) __builtin_amdgcn_mfma_f32_16x16x32_f16(A,B,C,0,0,0)
#define PKRTZ(a,b) __builtin_bit_cast(f16x2, __builtin_amdgcn_cvt_pkrtz(a,b))

__device__ __forceinline__ float hswish_clamp(float t) {   // med3(t+3,0,6)
  return __builtin_amdgcn_fmed3f(t + 3.f, 0.f, 6.f);
}
__device__ __forceinline__ f16x2 hsw_pk(f16x2 t) {         // t * clamp(t+3,0,6), packed
  const f16x2 c3 = {(_Float16)3.0f, (_Float16)3.0f};
  const f16x2 c0 = {(_Float16)0.0f, (_Float16)0.0f};
  const f16x2 c6 = {(_Float16)6.0f, (_Float16)6.0f};
  f16x2 u = t + c3;
  u = __builtin_elementwise_min(__builtin_elementwise_max(u, c0), c6);
  return t * u;
}

// h swizzle: row-major [32][32] f32, 16B chunks XOR'd by row&7.
__device__ __forceinline__ int hws(int row, int c) {
  return (row << 5) + ((((c >> 2) ^ (row & 7)) << 2) | (c & 3));
}

// ws: 16 regions of 34816 B (per layer/branch) + region 16 (fc1): 8704 B
//   region lb<16: [0,16384) w1f frags | [16384,32768) w2f frags (k-permuted, /6)
//                 [32768,...) f32: b1[256], b2[32], gamma[32], beta[32]
//   region 16:    [0,8192) fc1 frags (512 slots) | [8192,8704) fc1_b[128] f32
__global__ void prep_weights(const float* __restrict__ w11, const float* __restrict__ b11,
                             const float* __restrict__ w12, const float* __restrict__ b12,
                             const float* __restrict__ g1,  const float* __restrict__ be1,
                             const float* __restrict__ w21, const float* __restrict__ b21,
                             const float* __restrict__ w22, const float* __restrict__ b22,
                             const float* __restrict__ g2,  const float* __restrict__ be2,
                             const float* __restrict__ fc1w, const float* __restrict__ fc1b,
                             char* __restrict__ ws)
{
  const int lb = blockIdx.x;          // 0..16
  const int t = threadIdx.x;
  if (lb == 16) {                     // fc1 [128][32] -> GEMM1-style frags
    char* o = ws + (size_t)16 * 34816;
    _Float16* wf = (_Float16*)o;
    float* pr = (float*)(o + 8192);
    #pragma unroll
    for (int i = 0; i < 2; ++i) {
      int s = t + i*256;
      int lane = s & 63;
      int row = (s >> 6)*16 + (lane & 15);        // e index (0..127)
      int kb  = ((lane >> 4) & 3) * 8;
      const float* src = fc1w + row*32 + kb;
      #pragma unroll
      for (int j = 0; j < 8; ++j) wf[s*8 + j] = (_Float16)src[j];
    }
    if (t < 128) pr[t] = fc1b[t];
    return;
  }
  const int lay = lb >> 1, br = lb & 1;
  const float* w1  = (br ? w21 : w11) + lay*8192;   // [256][32]
  const float* w2  = (br ? w22 : w12) + lay*8192;   // [32][256]
  const float* bb1 = (br ? b21 : b11) + lay*256;
  const float* bb2 = (br ? b22 : b12) + lay*32;
  const float* gg  = (br ? g2  : g1 ) + lay*32;
  const float* bb  = (br ? be2 : be1) + lay*32;
  char* o = ws + (size_t)lb * 34816;
  _Float16* w1f = (_Float16*)o;
  _Float16* w2f = (_Float16*)(o + 16384);
  float* pr  = (float*)(o + 32768);
  // GEMM1 A-frag: slot s = dt*64+lane; elem j = w1[dt*16 + (lane&15)][8*(lane>>4)+j]
  #pragma unroll
  for (int i = 0; i < 4; ++i) {
    int s = t + i*256;
    int lane = s & 63;
    int row = (s >> 6)*16 + (lane & 15);
    int kb  = ((lane >> 4) & 3) * 8;
    const float* src = w1 + row*32 + kb;
    #pragma unroll
    for (int j = 0; j < 8; ++j) w1f[s*8 + j] = (_Float16)src[j];
  }
  // GEMM2 A-frag (k-permuted): slot s=(t*2+nt)*64+lane; n=nt*16+(lane&15); q=(lane>>4)&3
  #pragma unroll
  for (int i = 0; i < 4; ++i) {
    int s = t + i*256;
    int lane = s & 63;
    int tt = s >> 7;
    int nt = (s >> 6) & 1;
    int n  = nt*16 + (lane & 15);
    int qq = (lane >> 4) & 3;
    const float* src = w2 + n*256 + tt*32 + qq*4;
    _Float16* dst = w2f + s*8;
    #pragma unroll
    for (int j = 0; j < 4; ++j) dst[j]     = (_Float16)(src[j]      * (1.0f/6.0f));
    #pragma unroll
    for (int j = 0; j < 4; ++j) dst[4 + j] = (_Float16)(src[16 + j] * (1.0f/6.0f));
  }
  pr[t] = bb1[t];
  if (t < 32)      pr[256 + t] = bb2[t];
  else if (t < 64) pr[256 + t] = gg[t - 32];
  else if (t < 96) pr[256 + t] = bb[t - 64];
}

// 1 sample per wave. Per-wave LDS: h[1024] f32 swizzled + stats 32 x (mean,rstd).
// Wave-private -> ZERO barriers (same-wave LDS ordering is program-order).
// grid 2048 x 256thr = 8192 waves = exactly 8 blocks/CU on 256 CUs.
__global__ __launch_bounds__(256, 8)
void mixer_mfma(const float* __restrict__ x,
                const float* __restrict__ conv_w, const float* __restrict__ conv_b,
                const float* __restrict__ fc0_w,  const float* __restrict__ fc0_b,
                const char*  __restrict__ ws,
                const float* __restrict__ fcout_w, const float* __restrict__ fcout_b,
                float* __restrict__ out)
{
  __shared__ float smem[4 * 1088];     // 17408 B
  const int tid = threadIdx.x;
  const int wv  = tid >> 6;
  const int lid = tid & 63;
  const int ml  = lid & 15;
  const int q   = lid >> 4;
  const int q4  = q << 2, q8 = q << 3;
  const int sl  = lid >> 5, r = lid & 31;
  const int r7  = r & 7;

  float* hW  = smem + wv * 1088;       // [1024] swizzled h (one sample)
  float* stW = hW + 1024;              // [32] x (mean, rstd)

  const size_t b = (size_t)blockIdx.x * 4 + (size_t)wv;

  // ---------------- prologue: conv 3->1 + fc0 (staged via LDS, low-reg) ------
  {
    const float* xb = x + b*3072 + r*32;
    const float cw0 = conv_w[0], cw1 = conv_w[1], cw2 = conv_w[2], cb = conv_b[0];
    f32x4* hp = (f32x4*)(hW + (r << 5));
    // phase 1: grey row r, chunks split by sl (4 each)
    #pragma unroll
    for (int cc = 0; cc < 4; ++cc) {
      const int a = sl*4 + cc;
      f32x4 a0 = *(const f32x4*)(xb + a*4);
      f32x4 a1 = *(const f32x4*)(xb + 1024 + a*4);
      f32x4 a2 = *(const f32x4*)(xb + 2048 + a*4);
      f32x4 g4;
      #pragma unroll
      for (int e = 0; e < 4; ++e) g4[e] = cw0*a0[e] + cw1*a1[e] + cw2*a2[e] + cb;
      hp[a ^ r7] = g4;
    }
    // phase 2: fc0 — lane computes 16 outputs j = sl*16 + jj (reads after writes, lockstep)
    float accs[16];
    #pragma unroll
    for (int jj = 0; jj < 16; ++jj) accs[jj] = fc0_b[sl*16 + jj];
    #pragma unroll
    for (int a = 0; a < 8; ++a) {
      f32x4 g4 = hp[a ^ r7];
      #pragma unroll
      for (int jj = 0; jj < 16; ++jj) {
        const f32x4 w4 = *(const f32x4*)(fc0_w + (sl*16 + jj)*32 + a*4);
        accs[jj] += g4[0]*w4[0] + g4[1]*w4[1] + g4[2]*w4[2] + g4[3]*w4[3];
      }
    }
    // phase 3: write h0 row r, chunks sl*4..sl*4+3 (all reads done, lockstep)
    #pragma unroll
    for (int cc = 0; cc < 4; ++cc) {
      f32x4 w4;
      #pragma unroll
      for (int e = 0; e < 4; ++e) w4[e] = accs[cc*4 + e];
      hp[(sl*4 + cc) ^ r7] = w4;
    }
  }

  // ---------------- 32 mixing branch-steps, barrier-free ----------------
  for (int lay = 0; lay < LNUM; ++lay)
  for (int rep = 0; rep < 2; ++rep)
  for (int br = 0; br < 2; ++br) {
    const char* wsb = ws + (size_t)(lay*2 + br) * 34816;
    const f16x8* w1f = (const f16x8*)wsb;               // global, L1-hot
    const f16x8* w2f = (const f16x8*)(wsb + 16384);
    const float* pb1 = (const float*)(wsb + 32768);
    const float* pb2 = pb1 + 256;
    const float* pg  = pb1 + 288;
    const float* pbt = pb1 + 320;

    // per-row LN stats (both sl halves duplicate; same-addr same-data write ok)
    {
      const f32x4* hp = (const f32x4*)(hW + (r << 5));
      float sum = 0.f, sq = 0.f;
      #pragma unroll
      for (int a = 0; a < 8; ++a) {
        f32x4 v = hp[a ^ r7];
        #pragma unroll
        for (int e = 0; e < 4; ++e) { sum += v[e]; sq += v[e]*v[e]; }
      }
      float m = sum * (1.f/32.f);
      float rstd = rsqrtf(sq*(1.f/32.f) - m*m + 1e-5f);
      *(f32x2*)(stW + r*2) = (f32x2){m, rstd};
    }

    // GEMM1 B-fragments (f16): lane -> col m = mt*16+ml, k = 8q..8q+7
    f16x8 b1[2];
    if (br == 0) {      // token: Act[m=c][k=row] = LN(h)[row][c]  (column reads)
      const float ga = pg[ml],  gb = pg[16 + ml];
      const float ba = pbt[ml], bb2v = pbt[16 + ml];
      #pragma unroll
      for (int i = 0; i < 8; ++i) {
        const int k = q8 + i;
        f32x2 st = *(const f32x2*)(stW + k*2);
        float v0 = hW[hws(k, ml)];
        float v1 = hW[hws(k, 16 + ml)];
        b1[0][i] = (_Float16)((v0 - st[0]) * st[1] * ga + ba);
        b1[1][i] = (_Float16)((v1 - st[0]) * st[1] * gb + bb2v);
      }
    } else {            // channel: Act[m=row][k] = LN(h)[row][k]  (b128 row reads)
      f32x4 g0 = *(const f32x4*)(pg + q8);
      f32x4 g1 = *(const f32x4*)(pg + q8 + 4);
      f32x4 t0 = *(const f32x4*)(pbt + q8);
      f32x4 t1 = *(const f32x4*)(pbt + q8 + 4);
      #pragma unroll
      for (int mt = 0; mt < 2; ++mt) {
        const int row = (mt << 4) + ml;
        f32x2 st = *(const f32x2*)(stW + row*2);
        const f32x4* hr = (const f32x4*)(hW + (row << 5));
        f32x4 v0 = hr[(2*q)     ^ (row & 7)];
        f32x4 v1 = hr[(2*q + 1) ^ (row & 7)];
        #pragma unroll
        for (int e = 0; e < 4; ++e) {
          b1[mt][e]     = (_Float16)((v0[e] - st[0]) * st[1] * g0[e] + t0[e]);
          b1[mt][4 + e] = (_Float16)((v1[e] - st[0]) * st[1] * g1[e] + t1[e]);
        }
      }
    }

    // fused GEMM1 -> packed-f16 hardswish -> GEMM2
    f32x4 acc2[2][2];
    {
      f32x4 i0 = *(const f32x4*)(pb2 + q4);
      f32x4 i1 = *(const f32x4*)(pb2 + 16 + q4);
      #pragma unroll
      for (int mt = 0; mt < 2; ++mt) { acc2[0][mt] = i0; acc2[1][mt] = i1; }
    }
    #pragma unroll 2
    for (int t = 0; t < 8; ++t) {
      f16x8 a1a = w1f[(t*2 + 0)*64 + lid];
      f16x8 a1b = w1f[(t*2 + 1)*64 + lid];
      f32x4 biasa = *(const f32x4*)(pb1 + t*32 + q4);
      f32x4 biasb = *(const f32x4*)(pb1 + t*32 + 16 + q4);
      f16x8 a2a = w2f[(t*2 + 0)*64 + lid];
      f16x8 a2b = w2f[(t*2 + 1)*64 + lid];
      #pragma unroll
      for (int mt = 0; mt < 2; ++mt) {
        f32x4 c1a = MFMAH(a1a, b1[mt], biasa);            // C1T[d][m], d=32t+4q+rg
        f32x4 c1b = MFMAH(a1b, b1[mt], biasb);            // d=32t+16+4q+rg
        union { f16x2 h2[4]; f16x8 v; } b2u;
        b2u.h2[0] = hsw_pk(PKRTZ(c1a[0], c1a[1]));        // 1/6 folded into W2
        b2u.h2[1] = hsw_pk(PKRTZ(c1a[2], c1a[3]));
        b2u.h2[2] = hsw_pk(PKRTZ(c1b[0], c1b[1]));
        b2u.h2[3] = hsw_pk(PKRTZ(c1b[2], c1b[3]));
        acc2[0][mt] = MFMAH(a2a, b2u.v, acc2[0][mt]);     // C2T[n][m]
        acc2[1][mt] = MFMAH(a2b, b2u.v, acc2[1][mt]);
      }
    }

    // residual RMW
    if (br == 0) {      // token: h[n][c] += C2T[n][m=c]
      #pragma unroll
      for (int mt = 0; mt < 2; ++mt) {
        const int c = (mt << 4) + ml;
        #pragma unroll
        for (int nt = 0; nt < 2; ++nt)
        #pragma unroll
        for (int rg = 0; rg < 4; ++rg) {
          const int n = (nt << 4) + q4 + rg;
          hW[hws(n, c)] += acc2[nt][mt][rg];
        }
      }
    } else {            // channel: h[row][n..n+3] += acc2 (b128 RMW)
      #pragma unroll
      for (int mt = 0; mt < 2; ++mt) {
        const int row = (mt << 4) + ml;
        f32x4* hr = (f32x4*)(hW + (row << 5));
        #pragma unroll
        for (int nt = 0; nt < 2; ++nt) {
          const int a = ((nt << 2) + q) ^ (row & 7);
          f32x4 v = hr[a];
          v += acc2[nt][mt];
          hr[a] = v;
        }
      }
    }
  }

  // ------------- epilogue: fc1 (MFMA) + hardswish + pool + fcout -------------
  {
    const f16x8* fc1f = (const f16x8*)(ws + (size_t)16 * 34816);
    const float* fb   = (const float*)(ws + (size_t)16 * 34816 + 8192);
    // B-frag from raw h rows
    f16x8 be[2];
    #pragma unroll
    for (int mt = 0; mt < 2; ++mt) {
      const int row = (mt << 4) + ml;
      const f32x4* hr = (const f32x4*)(hW + (row << 5));
      f32x4 v0 = hr[(2*q)     ^ (row & 7)];
      f32x4 v1 = hr[(2*q + 1) ^ (row & 7)];
      #pragma unroll
      for (int e = 0; e < 4; ++e) {
        be[mt][e]     = (_Float16)v0[e];
        be[mt][4 + e] = (_Float16)v1[e];
      }
    }
    float pl[4][2] = {};                 // partial pools [t][mt]
    #pragma unroll
    for (int dt = 0; dt < 8; ++dt) {
      f16x8 af = fc1f[dt*64 + lid];
      f32x4 bias4 = *(const f32x4*)(fb + dt*16 + q4);
      #pragma unroll
      for (int mt = 0; mt < 2; ++mt) {
        f32x4 c = MFMAH(af, be[mt], bias4);          // e = dt*16+4q+rg, col=row
        float s = 0.f;
        #pragma unroll
        for (int rg = 0; rg < 4; ++rg) s += c[rg] * hswish_clamp(c[rg]);
        pl[dt >> 1][mt] += s;                        // raw sum (1/6,1/32 folded later)
      }
    }
    // reduce over the 4 q-groups
    #pragma unroll
    for (int t = 0; t < 4; ++t)
    #pragma unroll
    for (int mt = 0; mt < 2; ++mt) {
      float v = pl[t][mt];
      v += __shfl_xor(v, 16);
      v += __shfl_xor(v, 32);
      pl[t][mt] = v;
    }
    // publish pooled[row*4+t] (h dead; duplicate same-value writes ok)
    #pragma unroll
    for (int mt = 0; mt < 2; ++mt)
    #pragma unroll
    for (int t = 0; t < 4; ++t)
      hW[((mt << 4) + ml)*4 + t] = pl[t][mt];
    // fcout: 10 outputs, scale 1/(6*32)
    if (lid < 10) {
      const float* wr = fcout_w + lid*128;
      float acc = 0.f;
      #pragma unroll
      for (int m4 = 0; m4 < 32; ++m4) {
        f32x4 pv = *(const f32x4*)(hW + m4*4);
        f32x4 w4 = *(const f32x4*)(wr + m4*4);
        acc += pv[0]*w4[0] + pv[1]*w4[1] + pv[2]*w4[2] + pv[3]*w4[3];
      }
      out[b*10 + lid] = fcout_b[lid] + acc * (1.f/192.f);
    }
  }
}

extern "C" void kernel_launch(void* const* d_in, const int* in_sizes, int n_in,
                              void* d_out, int out_size, void* d_ws, size_t ws_size,
                              hipStream_t stream) {
  (void)in_sizes; (void)n_in; (void)out_size; (void)ws_size;
  const float* x       = (const float*)d_in[0];
  const float* conv_w  = (const float*)d_in[1];
  const float* conv_b  = (const float*)d_in[2];
  const float* fc0_w   = (const float*)d_in[3];
  const float* fc0_b   = (const float*)d_in[4];
  const float* ln1_g   = (const float*)d_in[5];
  const float* ln1_b   = (const float*)d_in[6];
  const float* w11     = (const float*)d_in[7];
  const float* b11     = (const float*)d_in[8];
  const float* w12     = (const float*)d_in[9];
  const float* b12     = (const float*)d_in[10];
  const float* ln2_g   = (const float*)d_in[11];
  const float* ln2_b   = (const float*)d_in[12];
  const float* w21     = (const float*)d_in[13];
  const float* b21     = (const float*)d_in[14];
  const float* w22     = (const float*)d_in[15];
  const float* b22     = (const float*)d_in[16];
  const float* fc1_w   = (const float*)d_in[17];
  const float* fc1_b   = (const float*)d_in[18];
  const float* fcout_w = (const float*)d_in[19];
  const float* fcout_b = (const float*)d_in[20];
  float* out = (float*)d_out;
  char* ws = (char*)d_ws;   // 17 * 34816 = 591872 B used (region 16 partially)

  prep_weights<<<17, 256, 0, stream>>>(w11, b11, w12, b12, ln1_g, ln1_b,
                                       w21, b21, w22, b22, ln2_g, ln2_b,
                                       fc1_w, fc1_b, ws);
  mixer_mfma<<<2048, 256, 0, stream>>>(x, conv_w, conv_b, fc0_w, fc0_b,
                                       (const char*)ws, fcout_w, fcout_b, out);
}

// Round 9
// 619.388 us; speedup vs baseline: 2.1811x; 2.1811x over previous
//
#include <hip/hip_runtime.h>

#define LNUM 8

typedef __attribute__((ext_vector_type(4))) float f32x4;
typedef __attribute__((ext_vector_type(2))) float f32x2;
typedef __attribute__((ext_vector_type(8))) _Float16 f16x8;
typedef __attribute__((ext_vector_type(2))) _Float16 f16x2;

#define MFMAH(A,B,C) __builtin_amdgcn_mfma_f32_16x16x32_f16(A,B,C,0,0,0)
#define PKRTZ(a,b) __builtin_bit_cast(f16x2, __builtin_amdgcn_cvt_pkrtz(a,b))

__device__ __forceinline__ float hswish_clamp(float t) {   // med3(t+3,0,6)
  return __builtin_amdgcn_fmed3f(t + 3.f, 0.f, 6.f);
}
__device__ __forceinline__ f16x2 hsw_pk(f16x2 t) {         // t * clamp(t+3,0,6), packed
  const f16x2 c3 = {(_Float16)3.0f, (_Float16)3.0f};
  const f16x2 c0 = {(_Float16)0.0f, (_Float16)0.0f};
  const f16x2 c6 = {(_Float16)6.0f, (_Float16)6.0f};
  f16x2 u = t + c3;
  u = __builtin_elementwise_min(__builtin_elementwise_max(u, c0), c6);
  return t * u;
}

// h swizzle: row-major [32][32] f32, 16B chunks XOR'd by row&7.
__device__ __forceinline__ int hws(int row, int c) {
  return (row << 5) + ((((c >> 2) ^ (row & 7)) << 2) | (c & 3));
}

// ws: 16 regions of 34816 B (per layer/branch) + region 16 (fc1): 8704 B
__global__ void prep_weights(const float* __restrict__ w11, const float* __restrict__ b11,
                             const float* __restrict__ w12, const float* __restrict__ b12,
                             const float* __restrict__ g1,  const float* __restrict__ be1,
                             const float* __restrict__ w21, const float* __restrict__ b21,
                             const float* __restrict__ w22, const float* __restrict__ b22,
                             const float* __restrict__ g2,  const float* __restrict__ be2,
                             const float* __restrict__ fc1w, const float* __restrict__ fc1b,
                             char* __restrict__ ws)
{
  const int lb = blockIdx.x;          // 0..16
  const int t = threadIdx.x;
  if (lb == 16) {                     // fc1 [128][32] -> GEMM1-style frags
    char* o = ws + (size_t)16 * 34816;
    _Float16* wf = (_Float16*)o;
    float* pr = (float*)(o + 8192);
    #pragma unroll
    for (int i = 0; i < 2; ++i) {
      int s = t + i*256;
      int lane = s & 63;
      int row = (s >> 6)*16 + (lane & 15);        // e index (0..127)
      int kb  = ((lane >> 4) & 3) * 8;
      const float* src = fc1w + row*32 + kb;
      #pragma unroll
      for (int j = 0; j < 8; ++j) wf[s*8 + j] = (_Float16)src[j];
    }
    if (t < 128) pr[t] = fc1b[t];
    return;
  }
  const int lay = lb >> 1, br = lb & 1;
  const float* w1  = (br ? w21 : w11) + lay*8192;   // [256][32]
  const float* w2  = (br ? w22 : w12) + lay*8192;   // [32][256]
  const float* bb1 = (br ? b21 : b11) + lay*256;
  const float* bb2 = (br ? b22 : b12) + lay*32;
  const float* gg  = (br ? g2  : g1 ) + lay*32;
  const float* bb  = (br ? be2 : be1) + lay*32;
  char* o = ws + (size_t)lb * 34816;
  _Float16* w1f = (_Float16*)o;
  _Float16* w2f = (_Float16*)(o + 16384);
  float* pr  = (float*)(o + 32768);
  // GEMM1 A-frag: slot s = dt*64+lane; elem j = w1[dt*16 + (lane&15)][8*(lane>>4)+j]
  #pragma unroll
  for (int i = 0; i < 4; ++i) {
    int s = t + i*256;
    int lane = s & 63;
    int row = (s >> 6)*16 + (lane & 15);
    int kb  = ((lane >> 4) & 3) * 8;
    const float* src = w1 + row*32 + kb;
    #pragma unroll
    for (int j = 0; j < 8; ++j) w1f[s*8 + j] = (_Float16)src[j];
  }
  // GEMM2 A-frag (k-permuted): slot s=(t*2+nt)*64+lane; n=nt*16+(lane&15); q=(lane>>4)&3
  #pragma unroll
  for (int i = 0; i < 4; ++i) {
    int s = t + i*256;
    int lane = s & 63;
    int tt = s >> 7;
    int nt = (s >> 6) & 1;
    int n  = nt*16 + (lane & 15);
    int qq = (lane >> 4) & 3;
    const float* src = w2 + n*256 + tt*32 + qq*4;
    _Float16* dst = w2f + s*8;
    #pragma unroll
    for (int j = 0; j < 4; ++j) dst[j]     = (_Float16)(src[j]      * (1.0f/6.0f));
    #pragma unroll
    for (int j = 0; j < 4; ++j) dst[4 + j] = (_Float16)(src[16 + j] * (1.0f/6.0f));
  }
  pr[t] = bb1[t];
  if (t < 32)      pr[256 + t] = bb2[t];
  else if (t < 64) pr[256 + t] = gg[t - 32];
  else if (t < 96) pr[256 + t] = bb[t - 64];
}

// 1 sample per wave. Per-wave LDS: h[1024] f32 swizzled + stats 32 x (mean,rstd).
// Wave-private -> ZERO barriers. launch_bounds (256,4): 128 unified regs/wave
// (R8's (256,8)=64 regs caused 4 GB of scratch spill traffic — never again).
__global__ __launch_bounds__(256, 4)
void mixer_mfma(const float* __restrict__ x,
                const float* __restrict__ conv_w, const float* __restrict__ conv_b,
                const float* __restrict__ fc0_w,  const float* __restrict__ fc0_b,
                const char*  __restrict__ ws,
                const float* __restrict__ fcout_w, const float* __restrict__ fcout_b,
                float* __restrict__ out)
{
  __shared__ float smem[4 * 1088];     // 17408 B
  const int tid = threadIdx.x;
  const int wv  = tid >> 6;
  const int lid = tid & 63;
  const int ml  = lid & 15;
  const int q   = lid >> 4;
  const int q4  = q << 2, q8 = q << 3;
  const int sl  = lid >> 5, r = lid & 31;
  const int r7  = r & 7;

  float* hW  = smem + wv * 1088;       // [1024] swizzled h (one sample)
  float* stW = hW + 1024;              // [32] x (mean, rstd)

  const size_t b = (size_t)blockIdx.x * 4 + (size_t)wv;

  // ---------------- prologue: conv 3->1 + fc0 (staged via LDS, low-reg) ------
  {
    const float* xb = x + b*3072 + r*32;
    const float cw0 = conv_w[0], cw1 = conv_w[1], cw2 = conv_w[2], cb = conv_b[0];
    f32x4* hp = (f32x4*)(hW + (r << 5));
    // phase 1: grey row r, chunks split by sl (4 each)
    #pragma unroll
    for (int cc = 0; cc < 4; ++cc) {
      const int a = sl*4 + cc;
      f32x4 a0 = *(const f32x4*)(xb + a*4);
      f32x4 a1 = *(const f32x4*)(xb + 1024 + a*4);
      f32x4 a2 = *(const f32x4*)(xb + 2048 + a*4);
      f32x4 g4;
      #pragma unroll
      for (int e = 0; e < 4; ++e) g4[e] = cw0*a0[e] + cw1*a1[e] + cw2*a2[e] + cb;
      hp[a ^ r7] = g4;
    }
    // phase 2: fc0 — lane computes 16 outputs j = sl*16 + jj (reads after writes, lockstep)
    float accs[16];
    #pragma unroll
    for (int jj = 0; jj < 16; ++jj) accs[jj] = fc0_b[sl*16 + jj];
    #pragma unroll
    for (int a = 0; a < 8; ++a) {
      f32x4 g4 = hp[a ^ r7];
      #pragma unroll
      for (int jj = 0; jj < 16; ++jj) {
        const f32x4 w4 = *(const f32x4*)(fc0_w + (sl*16 + jj)*32 + a*4);
        accs[jj] += g4[0]*w4[0] + g4[1]*w4[1] + g4[2]*w4[2] + g4[3]*w4[3];
      }
    }
    // phase 3: write h0 row r, chunks sl*4..sl*4+3 (all reads done, lockstep)
    #pragma unroll
    for (int cc = 0; cc < 4; ++cc) {
      f32x4 w4;
      #pragma unroll
      for (int e = 0; e < 4; ++e) w4[e] = accs[cc*4 + e];
      hp[(sl*4 + cc) ^ r7] = w4;
    }
  }

  // ---------------- 32 mixing branch-steps, barrier-free ----------------
  for (int lay = 0; lay < LNUM; ++lay)
  for (int rep = 0; rep < 2; ++rep)
  for (int br = 0; br < 2; ++br) {
    const char* wsb = ws + (size_t)(lay*2 + br) * 34816;
    const f16x8* w1f = (const f16x8*)wsb;               // global, L1-hot
    const f16x8* w2f = (const f16x8*)(wsb + 16384);
    const float* pb1 = (const float*)(wsb + 32768);
    const float* pb2 = pb1 + 256;
    const float* pg  = pb1 + 288;
    const float* pbt = pb1 + 320;

    // per-row LN stats; only half-wave writes (avoid dup same-address writes)
    {
      const f32x4* hp = (const f32x4*)(hW + (r << 5));
      float sum = 0.f, sq = 0.f;
      #pragma unroll
      for (int a = 0; a < 8; ++a) {
        f32x4 v = hp[a ^ r7];
        #pragma unroll
        for (int e = 0; e < 4; ++e) { sum += v[e]; sq += v[e]*v[e]; }
      }
      float m = sum * (1.f/32.f);
      float rstd = rsqrtf(sq*(1.f/32.f) - m*m + 1e-5f);
      if (lid < 32) *(f32x2*)(stW + r*2) = (f32x2){m, rstd};
    }

    // GEMM1 B-fragments (f16): lane -> col m = mt*16+ml, k = 8q..8q+7
    f16x8 b1[2];
    if (br == 0) {      // token: Act[m=c][k=row] = LN(h)[row][c]  (column reads)
      const float ga = pg[ml],  gb = pg[16 + ml];
      const float ba = pbt[ml], bb2v = pbt[16 + ml];
      #pragma unroll
      for (int i = 0; i < 8; ++i) {
        const int k = q8 + i;
        f32x2 st = *(const f32x2*)(stW + k*2);
        float v0 = hW[hws(k, ml)];
        float v1 = hW[hws(k, 16 + ml)];
        b1[0][i] = (_Float16)((v0 - st[0]) * st[1] * ga + ba);
        b1[1][i] = (_Float16)((v1 - st[0]) * st[1] * gb + bb2v);
      }
    } else {            // channel: Act[m=row][k] = LN(h)[row][k]  (b128 row reads)
      f32x4 g0 = *(const f32x4*)(pg + q8);
      f32x4 g1 = *(const f32x4*)(pg + q8 + 4);
      f32x4 t0 = *(const f32x4*)(pbt + q8);
      f32x4 t1 = *(const f32x4*)(pbt + q8 + 4);
      #pragma unroll
      for (int mt = 0; mt < 2; ++mt) {
        const int row = (mt << 4) + ml;
        f32x2 st = *(const f32x2*)(stW + row*2);
        const f32x4* hr = (const f32x4*)(hW + (row << 5));
        f32x4 v0 = hr[(2*q)     ^ (row & 7)];
        f32x4 v1 = hr[(2*q + 1) ^ (row & 7)];
        #pragma unroll
        for (int e = 0; e < 4; ++e) {
          b1[mt][e]     = (_Float16)((v0[e] - st[0]) * st[1] * g0[e] + t0[e]);
          b1[mt][4 + e] = (_Float16)((v1[e] - st[0]) * st[1] * g1[e] + t1[e]);
        }
      }
    }

    // fused GEMM1 -> packed-f16 hardswish -> GEMM2
    f32x4 acc2[2][2];
    {
      f32x4 i0 = *(const f32x4*)(pb2 + q4);
      f32x4 i1 = *(const f32x4*)(pb2 + 16 + q4);
      #pragma unroll
      for (int mt = 0; mt < 2; ++mt) { acc2[0][mt] = i0; acc2[1][mt] = i1; }
    }
    #pragma unroll 2
    for (int t = 0; t < 8; ++t) {
      f16x8 a1a = w1f[(t*2 + 0)*64 + lid];
      f16x8 a1b = w1f[(t*2 + 1)*64 + lid];
      f32x4 biasa = *(const f32x4*)(pb1 + t*32 + q4);
      f32x4 biasb = *(const f32x4*)(pb1 + t*32 + 16 + q4);
      f16x8 a2a = w2f[(t*2 + 0)*64 + lid];
      f16x8 a2b = w2f[(t*2 + 1)*64 + lid];
      #pragma unroll
      for (int mt = 0; mt < 2; ++mt) {
        f32x4 c1a = MFMAH(a1a, b1[mt], biasa);            // C1T[d][m], d=32t+4q+rg
        f32x4 c1b = MFMAH(a1b, b1[mt], biasb);            // d=32t+16+4q+rg
        union { f16x2 h2[4]; f16x8 v; } b2u;
        b2u.h2[0] = hsw_pk(PKRTZ(c1a[0], c1a[1]));        // 1/6 folded into W2
        b2u.h2[1] = hsw_pk(PKRTZ(c1a[2], c1a[3]));
        b2u.h2[2] = hsw_pk(PKRTZ(c1b[0], c1b[1]));
        b2u.h2[3] = hsw_pk(PKRTZ(c1b[2], c1b[3]));
        acc2[0][mt] = MFMAH(a2a, b2u.v, acc2[0][mt]);     // C2T[n][m]
        acc2[1][mt] = MFMAH(a2b, b2u.v, acc2[1][mt]);
      }
    }

    // residual RMW
    if (br == 0) {      // token: h[n][c] += C2T[n][m=c]
      #pragma unroll
      for (int mt = 0; mt < 2; ++mt) {
        const int c = (mt << 4) + ml;
        #pragma unroll
        for (int nt = 0; nt < 2; ++nt)
        #pragma unroll
        for (int rg = 0; rg < 4; ++rg) {
          const int n = (nt << 4) + q4 + rg;
          hW[hws(n, c)] += acc2[nt][mt][rg];
        }
      }
    } else {            // channel: h[row][n..n+3] += acc2 (b128 RMW)
      #pragma unroll
      for (int mt = 0; mt < 2; ++mt) {
        const int row = (mt << 4) + ml;
        f32x4* hr = (f32x4*)(hW + (row << 5));
        #pragma unroll
        for (int nt = 0; nt < 2; ++nt) {
          const int a = ((nt << 2) + q) ^ (row & 7);
          f32x4 v = hr[a];
          v += acc2[nt][mt];
          hr[a] = v;
        }
      }
    }
  }

  // ------------- epilogue: fc1 (MFMA) + hardswish + pool + fcout -------------
  {
    const f16x8* fc1f = (const f16x8*)(ws + (size_t)16 * 34816);
    const float* fb   = (const float*)(ws + (size_t)16 * 34816 + 8192);
    // B-frag from raw h rows
    f16x8 be[2];
    #pragma unroll
    for (int mt = 0; mt < 2; ++mt) {
      const int row = (mt << 4) + ml;
      const f32x4* hr = (const f32x4*)(hW + (row << 5));
      f32x4 v0 = hr[(2*q)     ^ (row & 7)];
      f32x4 v1 = hr[(2*q + 1) ^ (row & 7)];
      #pragma unroll
      for (int e = 0; e < 4; ++e) {
        be[mt][e]     = (_Float16)v0[e];
        be[mt][4 + e] = (_Float16)v1[e];
      }
    }
    float pl[4][2] = {};                 // partial pools [t][mt]
    #pragma unroll
    for (int dt = 0; dt < 8; ++dt) {
      f16x8 af = fc1f[dt*64 + lid];
      f32x4 bias4 = *(const f32x4*)(fb + dt*16 + q4);
      #pragma unroll
      for (int mt = 0; mt < 2; ++mt) {
        f32x4 c = MFMAH(af, be[mt], bias4);          // e = dt*16+4q+rg, col=row
        float s = 0.f;
        #pragma unroll
        for (int rg = 0; rg < 4; ++rg) s += c[rg] * hswish_clamp(c[rg]);
        pl[dt >> 1][mt] += s;                        // raw sum (1/6,1/32 folded later)
      }
    }
    // reduce over the 4 q-groups
    #pragma unroll
    for (int t = 0; t < 4; ++t)
    #pragma unroll
    for (int mt = 0; mt < 2; ++mt) {
      float v = pl[t][mt];
      v += __shfl_xor(v, 16);
      v += __shfl_xor(v, 32);
      pl[t][mt] = v;
    }
    // publish pooled[row*4+t] (h dead; only q==0 lanes write to avoid dups)
    if (q == 0) {
      #pragma unroll
      for (int mt = 0; mt < 2; ++mt)
      #pragma unroll
      for (int t = 0; t < 4; ++t)
        hW[((mt << 4) + ml)*4 + t] = pl[t][mt];
    }
    // fcout: 10 outputs, scale 1/(6*32)
    if (lid < 10) {
      const float* wr = fcout_w + lid*128;
      float acc = 0.f;
      #pragma unroll
      for (int m4 = 0; m4 < 32; ++m4) {
        f32x4 pv = *(const f32x4*)(hW + m4*4);
        f32x4 w4 = *(const f32x4*)(wr + m4*4);
        acc += pv[0]*w4[0] + pv[1]*w4[1] + pv[2]*w4[2] + pv[3]*w4[3];
      }
      out[b*10 + lid] = fcout_b[lid] + acc * (1.f/192.f);
    }
  }
}

extern "C" void kernel_launch(void* const* d_in, const int* in_sizes, int n_in,
                              void* d_out, int out_size, void* d_ws, size_t ws_size,
                              hipStream_t stream) {
  (void)in_sizes; (void)n_in; (void)out_size; (void)ws_size;
  const float* x       = (const float*)d_in[0];
  const float* conv_w  = (const float*)d_in[1];
  const float* conv_b  = (const float*)d_in[2];
  const float* fc0_w   = (const float*)d_in[3];
  const float* fc0_b   = (const float*)d_in[4];
  const float* ln1_g   = (const float*)d_in[5];
  const float* ln1_b   = (const float*)d_in[6];
  const float* w11     = (const float*)d_in[7];
  const float* b11     = (const float*)d_in[8];
  const float* w12     = (const float*)d_in[9];
  const float* b12     = (const float*)d_in[10];
  const float* ln2_g   = (const float*)d_in[11];
  const float* ln2_b   = (const float*)d_in[12];
  const float* w21     = (const float*)d_in[13];
  const float* b21     = (const float*)d_in[14];
  const float* w22     = (const float*)d_in[15];
  const float* b22     = (const float*)d_in[16];
  const float* fc1_w   = (const float*)d_in[17];
  const float* fc1_b   = (const float*)d_in[18];
  const float* fcout_w = (const float*)d_in[19];
  const float* fcout_b = (const float*)d_in[20];
  float* out = (float*)d_out;
  char* ws = (char*)d_ws;   // 17 * 34816 = 591872 B used (region 16 partially)

  prep_weights<<<17, 256, 0, stream>>>(w11, b11, w12, b12, ln1_g, ln1_b,
                                       w21, b21, w22, b22, ln2_g, ln2_b,
                                       fc1_w, fc1_b, ws);
  mixer_mfma<<<2048, 256, 0, stream>>>(x, conv_w, conv_b, fc0_w, fc0_b,
                                       (const char*)ws, fcout_w, fcout_b, out);
}

// Round 10
// 430.493 us; speedup vs baseline: 3.1381x; 1.4388x over previous
//
#include <hip/hip_runtime.h>

#define LNUM 8

typedef __attribute__((ext_vector_type(4))) float f32x4;
typedef __attribute__((ext_vector_type(2))) float f32x2;
typedef __attribute__((ext_vector_type(8))) _Float16 f16x8;
typedef __attribute__((ext_vector_type(2))) _Float16 f16x2;

#define MFMAH(A,B,C) __builtin_amdgcn_mfma_f32_16x16x32_f16(A,B,C,0,0,0)
#define PKRTZ(a,b) __builtin_bit_cast(f16x2, __builtin_amdgcn_cvt_pkrtz(a,b))

__device__ __forceinline__ float hswish_clamp(float t) {   // med3(t+3,0,6)
  return __builtin_amdgcn_fmed3f(t + 3.f, 0.f, 6.f);
}
__device__ __forceinline__ f16x2 hsw_pk(f16x2 t) {         // t * clamp(t+3,0,6), packed
  const f16x2 c3 = {(_Float16)3.0f, (_Float16)3.0f};
  const f16x2 c0 = {(_Float16)0.0f, (_Float16)0.0f};
  const f16x2 c6 = {(_Float16)6.0f, (_Float16)6.0f};
  f16x2 u = t + c3;
  u = __builtin_elementwise_min(__builtin_elementwise_max(u, c0), c6);
  return t * u;
}

// h swizzle: row-major [32][32] f32, 16B chunks XOR'd by row&7.
__device__ __forceinline__ int hws(int row, int c) {
  return (row << 5) + ((((c >> 2) ^ (row & 7)) << 2) | (c & 3));
}

// ws: 16 regions of 34816 B (per layer/branch) + region 16 (fc1): 8704 B
__global__ void prep_weights(const float* __restrict__ w11, const float* __restrict__ b11,
                             const float* __restrict__ w12, const float* __restrict__ b12,
                             const float* __restrict__ g1,  const float* __restrict__ be1,
                             const float* __restrict__ w21, const float* __restrict__ b21,
                             const float* __restrict__ w22, const float* __restrict__ b22,
                             const float* __restrict__ g2,  const float* __restrict__ be2,
                             const float* __restrict__ fc1w, const float* __restrict__ fc1b,
                             char* __restrict__ ws)
{
  const int lb = blockIdx.x;          // 0..16
  const int t = threadIdx.x;
  if (lb == 16) {                     // fc1 [128][32] -> GEMM1-style frags
    char* o = ws + (size_t)16 * 34816;
    _Float16* wf = (_Float16*)o;
    float* pr = (float*)(o + 8192);
    #pragma unroll
    for (int i = 0; i < 2; ++i) {
      int s = t + i*256;
      int lane = s & 63;
      int row = (s >> 6)*16 + (lane & 15);        // e index (0..127)
      int kb  = ((lane >> 4) & 3) * 8;
      const float* src = fc1w + row*32 + kb;
      #pragma unroll
      for (int j = 0; j < 8; ++j) wf[s*8 + j] = (_Float16)src[j];
    }
    if (t < 128) pr[t] = fc1b[t];
    return;
  }
  const int lay = lb >> 1, br = lb & 1;
  const float* w1  = (br ? w21 : w11) + lay*8192;   // [256][32]
  const float* w2  = (br ? w22 : w12) + lay*8192;   // [32][256]
  const float* bb1 = (br ? b21 : b11) + lay*256;
  const float* bb2 = (br ? b22 : b12) + lay*32;
  const float* gg  = (br ? g2  : g1 ) + lay*32;
  const float* bb  = (br ? be2 : be1) + lay*32;
  char* o = ws + (size_t)lb * 34816;
  _Float16* w1f = (_Float16*)o;
  _Float16* w2f = (_Float16*)(o + 16384);
  float* pr  = (float*)(o + 32768);
  // GEMM1 A-frag: slot s = dt*64+lane; elem j = w1[dt*16 + (lane&15)][8*(lane>>4)+j]
  #pragma unroll
  for (int i = 0; i < 4; ++i) {
    int s = t + i*256;
    int lane = s & 63;
    int row = (s >> 6)*16 + (lane & 15);
    int kb  = ((lane >> 4) & 3) * 8;
    const float* src = w1 + row*32 + kb;
    #pragma unroll
    for (int j = 0; j < 8; ++j) w1f[s*8 + j] = (_Float16)src[j];
  }
  // GEMM2 A-frag (k-permuted): slot s=(t*2+nt)*64+lane; n=nt*16+(lane&15); q=(lane>>4)&3
  #pragma unroll
  for (int i = 0; i < 4; ++i) {
    int s = t + i*256;
    int lane = s & 63;
    int tt = s >> 7;
    int nt = (s >> 6) & 1;
    int n  = nt*16 + (lane & 15);
    int qq = (lane >> 4) & 3;
    const float* src = w2 + n*256 + tt*32 + qq*4;
    _Float16* dst = w2f + s*8;
    #pragma unroll
    for (int j = 0; j < 4; ++j) dst[j]     = (_Float16)(src[j]      * (1.0f/6.0f));
    #pragma unroll
    for (int j = 0; j < 4; ++j) dst[4 + j] = (_Float16)(src[16 + j] * (1.0f/6.0f));
  }
  pr[t] = bb1[t];
  if (t < 32)      pr[256 + t] = bb2[t];
  else if (t < 64) pr[256 + t] = gg[t - 32];
  else if (t < 96) pr[256 + t] = bb[t - 64];
}

// 2 samples per wave (R7 geometry). Per-wave LDS: 2x h[1024] swizzled + 64 stats pairs.
// Wave-private -> ZERO barriers. launch_bounds (256,3): <=170 unified regs ->
// room for ~100 arch VGPR + acc without spill (R7/R9's (256,4) forced 64 arch -> spill).
__global__ __launch_bounds__(256, 3)
void mixer_mfma(const float* __restrict__ x,
                const float* __restrict__ conv_w, const float* __restrict__ conv_b,
                const float* __restrict__ fc0_w,  const float* __restrict__ fc0_b,
                const char*  __restrict__ ws,
                const float* __restrict__ fcout_w, const float* __restrict__ fcout_b,
                float* __restrict__ out)
{
  __shared__ float smem[4 * 2176];     // 34816 B
  const int tid = threadIdx.x;
  const int wv  = tid >> 6;
  const int lid = tid & 63;
  const int ml  = lid & 15;
  const int q   = lid >> 4;
  const int q4  = q << 2, q8 = q << 3;
  const int sl  = lid >> 5, r = lid & 31;
  const int r7  = r & 7;

  float* hW  = smem + wv * 2176;       // [2][1024] swizzled h
  float* stW = hW + 2048;              // [2][32] x (mean, rstd)

  const size_t b0 = (size_t)blockIdx.x * 8 + (size_t)wv * 2;

  // ---------------- prologue: conv 3->1 + fc0 (store chunk-wise) ----------
  {
    const size_t b = b0 + sl;
    const float* xb = x + b*3072 + r*32;
    const float cw0 = conv_w[0], cw1 = conv_w[1], cw2 = conv_w[2], cb = conv_b[0];
    float g[32];
    #pragma unroll
    for (int j4 = 0; j4 < 8; ++j4) {
      f32x4 a0 = *(const f32x4*)(xb + j4*4);
      f32x4 a1 = *(const f32x4*)(xb + 1024 + j4*4);
      f32x4 a2 = *(const f32x4*)(xb + 2048 + j4*4);
      #pragma unroll
      for (int e = 0; e < 4; ++e)
        g[j4*4+e] = cw0*a0[e] + cw1*a1[e] + cw2*a2[e] + cb;
    }
    f32x4* hp = (f32x4*)(hW + sl*1024 + (r << 5));
    #pragma unroll
    for (int a = 0; a < 8; ++a) {
      f32x4 w;
      #pragma unroll
      for (int e = 0; e < 4; ++e) {
        const int j = a*4 + e;
        const float* wr = fc0_w + j*32;
        float acc = fc0_b[j];
        #pragma unroll
        for (int k = 0; k < 32; ++k) acc += g[k]*wr[k];
        w[e] = acc;
      }
      hp[a ^ r7] = w;      // store immediately, no second big array
    }
  }

  // ---------------- 32 mixing branch-steps, barrier-free ----------------
  for (int lay = 0; lay < LNUM; ++lay)
  for (int rep = 0; rep < 2; ++rep)
  for (int br = 0; br < 2; ++br) {
    const char* wsb = ws + (size_t)(lay*2 + br) * 34816;
    const f16x8* w1f = (const f16x8*)wsb;               // global, L1-hot
    const f16x8* w2f = (const f16x8*)(wsb + 16384);
    const float* pb1 = (const float*)(wsb + 32768);
    const float* pb2 = pb1 + 256;
    const float* pg  = pb1 + 288;
    const float* pbt = pb1 + 320;

    // per-row LN stats: lane (sl, r) owns one row
    {
      const f32x4* hp = (const f32x4*)(hW + sl*1024 + (r << 5));
      float sum = 0.f, sq = 0.f;
      #pragma unroll
      for (int a = 0; a < 8; ++a) {
        f32x4 v = hp[a ^ r7];
        #pragma unroll
        for (int e = 0; e < 4; ++e) { sum += v[e]; sq += v[e]*v[e]; }
      }
      float m = sum * (1.f/32.f);
      float rstd = rsqrtf(sq*(1.f/32.f) - m*m + 1e-5f);
      *(f32x2*)(stW + ((sl << 5) + r)*2) = (f32x2){m, rstd};
    }

    // GEMM1 B-fragments (f16): lane -> col m = mt*16+ml, k = 8q..8q+7
    f16x8 b1[4];
    if (br == 0) {      // token: Act[m=c][k=row] = LN(h)[row][c]  (column reads)
      const float ga = pg[ml],  gb = pg[16 + ml];
      const float ba = pbt[ml], bb2v = pbt[16 + ml];
      #pragma unroll
      for (int i = 0; i < 8; ++i) {
        const int k = q8 + i;
        f32x2 s0 = *(const f32x2*)(stW + k*2);
        f32x2 s1 = *(const f32x2*)(stW + 64 + k*2);
        #pragma unroll
        for (int mt = 0; mt < 4; ++mt) {
          const int samp = mt >> 1;
          const int c = ((mt & 1) << 4) + ml;
          f32x2 st = samp ? s1 : s0;
          float v = hW[samp*1024 + hws(k, c)];
          float g_ = (mt & 1) ? gb : ga;
          float be = (mt & 1) ? bb2v : ba;
          b1[mt][i] = (_Float16)((v - st[0]) * st[1] * g_ + be);
        }
      }
    } else {            // channel: Act[m=row][k] = LN(h)[row][k]  (b128 row reads)
      f32x4 g0 = *(const f32x4*)(pg + q8);
      f32x4 g1 = *(const f32x4*)(pg + q8 + 4);
      f32x4 t0 = *(const f32x4*)(pbt + q8);
      f32x4 t1 = *(const f32x4*)(pbt + q8 + 4);
      #pragma unroll
      for (int mt = 0; mt < 4; ++mt) {
        const int samp = mt >> 1;
        const int row = ((mt & 1) << 4) + ml;
        f32x2 st = *(const f32x2*)(stW + ((samp << 5) + row)*2);
        const f32x4* hr = (const f32x4*)(hW + samp*1024 + (row << 5));
        f32x4 v0 = hr[(2*q)     ^ (row & 7)];
        f32x4 v1 = hr[(2*q + 1) ^ (row & 7)];
        #pragma unroll
        for (int e = 0; e < 4; ++e) {
          b1[mt][e]     = (_Float16)((v0[e] - st[0]) * st[1] * g0[e] + t0[e]);
          b1[mt][4 + e] = (_Float16)((v1[e] - st[0]) * st[1] * g1[e] + t1[e]);
        }
      }
    }

    // fused GEMM1 -> packed-f16 hardswish -> GEMM2
    f32x4 acc2[2][4];
    {
      f32x4 i0 = *(const f32x4*)(pb2 + q4);
      f32x4 i1 = *(const f32x4*)(pb2 + 16 + q4);
      #pragma unroll
      for (int mt = 0; mt < 4; ++mt) { acc2[0][mt] = i0; acc2[1][mt] = i1; }
    }
    #pragma unroll 2
    for (int t = 0; t < 8; ++t) {
      f16x8 a1a = w1f[(t*2 + 0)*64 + lid];
      f16x8 a1b = w1f[(t*2 + 1)*64 + lid];
      f32x4 biasa = *(const f32x4*)(pb1 + t*32 + q4);
      f32x4 biasb = *(const f32x4*)(pb1 + t*32 + 16 + q4);
      f16x8 a2a = w2f[(t*2 + 0)*64 + lid];
      f16x8 a2b = w2f[(t*2 + 1)*64 + lid];
      #pragma unroll
      for (int mt = 0; mt < 4; ++mt) {
        f32x4 c1a = MFMAH(a1a, b1[mt], biasa);            // C1T[d][m], d=32t+4q+rg
        f32x4 c1b = MFMAH(a1b, b1[mt], biasb);            // d=32t+16+4q+rg
        union { f16x2 h2[4]; f16x8 v; } b2u;
        b2u.h2[0] = hsw_pk(PKRTZ(c1a[0], c1a[1]));        // 1/6 folded into W2
        b2u.h2[1] = hsw_pk(PKRTZ(c1a[2], c1a[3]));
        b2u.h2[2] = hsw_pk(PKRTZ(c1b[0], c1b[1]));
        b2u.h2[3] = hsw_pk(PKRTZ(c1b[2], c1b[3]));
        acc2[0][mt] = MFMAH(a2a, b2u.v, acc2[0][mt]);     // C2T[n][m]
        acc2[1][mt] = MFMAH(a2b, b2u.v, acc2[1][mt]);
      }
    }

    // residual RMW
    if (br == 0) {      // token: h[n][c] += C2T[n][m=c]
      #pragma unroll
      for (int mt = 0; mt < 4; ++mt) {
        const int samp = mt >> 1;
        const int c = ((mt & 1) << 4) + ml;
        float* hs = hW + samp*1024;
        #pragma unroll
        for (int nt = 0; nt < 2; ++nt)
        #pragma unroll
        for (int rg = 0; rg < 4; ++rg) {
          const int n = (nt << 4) + q4 + rg;
          hs[hws(n, c)] += acc2[nt][mt][rg];
        }
      }
    } else {            // channel: h[row][n..n+3] += acc2 (b128 RMW)
      #pragma unroll
      for (int mt = 0; mt < 4; ++mt) {
        const int samp = mt >> 1;
        const int row = ((mt & 1) << 4) + ml;
        f32x4* hr = (f32x4*)(hW + samp*1024 + (row << 5));
        #pragma unroll
        for (int nt = 0; nt < 2; ++nt) {
          const int a = ((nt << 2) + q) ^ (row & 7);
          f32x4 v = hr[a];
          v += acc2[nt][mt];
          hr[a] = v;
        }
      }
    }
  }

  // ------------- epilogue: fc1 (MFMA) + hardswish + pool + fcout -------------
  {
    const f16x8* fc1f = (const f16x8*)(ws + (size_t)16 * 34816);
    const float* fb   = (const float*)(ws + (size_t)16 * 34816 + 8192);
    // B-frags from raw h rows (both samples)
    f16x8 be[4];
    #pragma unroll
    for (int mt = 0; mt < 4; ++mt) {
      const int samp = mt >> 1;
      const int row = ((mt & 1) << 4) + ml;
      const f32x4* hr = (const f32x4*)(hW + samp*1024 + (row << 5));
      f32x4 v0 = hr[(2*q)     ^ (row & 7)];
      f32x4 v1 = hr[(2*q + 1) ^ (row & 7)];
      #pragma unroll
      for (int e = 0; e < 4; ++e) {
        be[mt][e]     = (_Float16)v0[e];
        be[mt][4 + e] = (_Float16)v1[e];
      }
    }
    float pl[4][4] = {};                 // partial pools [t][mt]
    #pragma unroll
    for (int dt = 0; dt < 8; ++dt) {
      f16x8 af = fc1f[dt*64 + lid];
      f32x4 bias4 = *(const f32x4*)(fb + dt*16 + q4);
      #pragma unroll
      for (int mt = 0; mt < 4; ++mt) {
        f32x4 c = MFMAH(af, be[mt], bias4);          // e = dt*16+4q+rg, col=row
        float s = 0.f;
        #pragma unroll
        for (int rg = 0; rg < 4; ++rg) s += c[rg] * hswish_clamp(c[rg]);
        pl[dt >> 1][mt] += s;                        // raw sum (1/6,1/32 folded later)
      }
    }
    // reduce over the 4 q-groups
    #pragma unroll
    for (int t = 0; t < 4; ++t)
    #pragma unroll
    for (int mt = 0; mt < 4; ++mt) {
      float v = pl[t][mt];
      v += __shfl_xor(v, 16);
      v += __shfl_xor(v, 32);
      pl[t][mt] = v;
    }
    // publish pooled[samp][row*4+t] from q==0 lanes (h dead; program-order safe)
    if (q == 0) {
      #pragma unroll
      for (int mt = 0; mt < 4; ++mt)
      #pragma unroll
      for (int t = 0; t < 4; ++t)
        hW[(mt >> 1)*1024 + (((mt & 1) << 4) + ml)*4 + t] = pl[t][mt];
    }
    // fcout: 10 outputs per sample, scale 1/(6*32)
    if (r < 10) {
      const float* pv = hW + sl*1024;
      const float* wr = fcout_w + r*128;
      float acc = 0.f;
      #pragma unroll
      for (int m4 = 0; m4 < 32; ++m4) {
        f32x4 p4 = *(const f32x4*)(pv + m4*4);
        f32x4 w4 = *(const f32x4*)(wr + m4*4);
        acc += p4[0]*w4[0] + p4[1]*w4[1] + p4[2]*w4[2] + p4[3]*w4[3];
      }
      out[(b0 + sl)*10 + r] = fcout_b[r] + acc * (1.f/192.f);
    }
  }
}

extern "C" void kernel_launch(void* const* d_in, const int* in_sizes, int n_in,
                              void* d_out, int out_size, void* d_ws, size_t ws_size,
                              hipStream_t stream) {
  (void)in_sizes; (void)n_in; (void)out_size; (void)ws_size;
  const float* x       = (const float*)d_in[0];
  const float* conv_w  = (const float*)d_in[1];
  const float* conv_b  = (const float*)d_in[2];
  const float* fc0_w   = (const float*)d_in[3];
  const float* fc0_b   = (const float*)d_in[4];
  const float* ln1_g   = (const float*)d_in[5];
  const float* ln1_b   = (const float*)d_in[6];
  const float* w11     = (const float*)d_in[7];
  const float* b11     = (const float*)d_in[8];
  const float* w12     = (const float*)d_in[9];
  const float* b12     = (const float*)d_in[10];
  const float* ln2_g   = (const float*)d_in[11];
  const float* ln2_b   = (const float*)d_in[12];
  const float* w21     = (const float*)d_in[13];
  const float* b21     = (const float*)d_in[14];
  const float* w22     = (const float*)d_in[15];
  const float* b22     = (const float*)d_in[16];
  const float* fc1_w   = (const float*)d_in[17];
  const float* fc1_b   = (const float*)d_in[18];
  const float* fcout_w = (const float*)d_in[19];
  const float* fcout_b = (const float*)d_in[20];
  float* out = (float*)d_out;
  char* ws = (char*)d_ws;   // 17 * 34816 = 591872 B used (region 16 partially)

  prep_weights<<<17, 256, 0, stream>>>(w11, b11, w12, b12, ln1_g, ln1_b,
                                       w21, b21, w22, b22, ln2_g, ln2_b,
                                       fc1_w, fc1_b, ws);
  mixer_mfma<<<1024, 256, 0, stream>>>(x, conv_w, conv_b, fc0_w, fc0_b,
                                       (const char*)ws, fcout_w, fcout_b, out);
}